// Round 11
// baseline (490.273 us; speedup 1.0000x reference)
//
#include <hip/hip_runtime.h>
#include <cstdint>

#define NT 256

// ws float offsets
static constexpr int W0T_OFF = 0;        // w0T[gc][32] : [2600][32] = 83200
static constexpr int W1T_OFF = 83200;    // w1T[k][o][28] : [50][52][28] = 72800
static constexpr int W2T_OFF = 156000;   // w2T[k][o][28] : 72800
static constexpr int CF_OFF  = 228800;   // gate coeffs float4 [3][1300] = 15600 floats
static constexpr int LG_OFF  = 244400;   // logits [B][10] f32
static constexpr int XT_OFF  = 408576;   // xT[256][B] (used only if ws_size allows)

// ---------------------------------------------------------------------------
// Precompute: softmax conn weights (axis=1) stored per-column contiguous,
// collapse 16-gate bank to gate(A,B) = a + b*A + c*B + d*A*B, zero logits.
// ---------------------------------------------------------------------------
__global__ void precompute_kernel(const float* __restrict__ c0,
                                  const float* __restrict__ w0,
                                  const float* __restrict__ c1,
                                  const float* __restrict__ w1,
                                  const float* __restrict__ c2,
                                  const float* __restrict__ w2,
                                  float* __restrict__ ws, int nz4) {
  int id = blockIdx.x * blockDim.x + threadIdx.x;
  if (id < 2600) {  // layer-1 col gc=(n,o): softmax over m=32 (stride 325 in src)
    int n = id / 325, o = id - n * 325;
    const float* src = c0 + n * (32 * 325) + o;
    float v[32]; float mx = -3.4e38f;
#pragma unroll
    for (int m = 0; m < 32; ++m) { v[m] = src[m * 325]; mx = fmaxf(mx, v[m]); }
    float ssum = 0.f;
#pragma unroll
    for (int m = 0; m < 32; ++m) { v[m] = __expf(v[m] - mx); ssum += v[m]; }
    float inv = 1.f / ssum;
    float* dst = ws + W0T_OFF + (size_t)id * 32;
#pragma unroll
    for (int m = 0; m < 32; ++m) dst[m] = v[m] * inv;
    return;
  }
  id -= 2600;
  if (id < 5200) {  // layer-2/3 col (k,o): softmax over m=26, pad stride 28
    const float* src0 = (id < 2600) ? c1 : c2;
    float* dst0 = ws + ((id < 2600) ? W1T_OFF : W2T_OFF);
    int col = (id < 2600) ? id : id - 2600;
    int k = col / 52, o = col - k * 52;
    const float* src = src0 + k * (26 * 52) + o;
    float v[26]; float mx = -3.4e38f;
#pragma unroll
    for (int m = 0; m < 26; ++m) { v[m] = src[m * 52]; mx = fmaxf(mx, v[m]); }
    float ssum = 0.f;
#pragma unroll
    for (int m = 0; m < 26; ++m) { v[m] = __expf(v[m] - mx); ssum += v[m]; }
    float inv = 1.f / ssum;
    float* dst = dst0 + (size_t)(k * 52 + o) * 28;
#pragma unroll
    for (int m = 0; m < 26; ++m) dst[m] = v[m] * inv;
    dst[26] = 0.f; dst[27] = 0.f;
    return;
  }
  id -= 5200;
  if (id < 3900) {  // gate coefficients
    int layer = id / 1300, g = id - layer * 1300;
    const float* w = (layer == 0) ? w0 : ((layer == 1) ? w1 : w2);
    float v[16]; float mx = -3.4e38f;
#pragma unroll
    for (int k = 0; k < 16; ++k) { v[k] = w[k * 1300 + g]; mx = fmaxf(mx, v[k]); }
    float ssum = 0.f;
#pragma unroll
    for (int k = 0; k < 16; ++k) { v[k] = __expf(v[k] - mx); ssum += v[k]; }
    float inv = 1.f / ssum;
#pragma unroll
    for (int k = 0; k < 16; ++k) v[k] *= inv;
    float alpha = v[8] + v[9] + v[10] + v[11] + v[12] + v[13] + v[14] + v[15];
    float beta  = v[2] + v[3] + v[6] + v[7] - v[8] - v[9] - v[12] - v[13];
    float gamma = v[4] + v[5] + v[6] + v[7] - v[8] - v[9] - v[10] - v[11];
    float delta = v[1] - v[2] - v[4] - 2.f * v[6] - v[7] + v[8] + 2.f * v[9]
                + v[11] + v[13] - v[14];
    reinterpret_cast<float4*>(ws + CF_OFF)[id] =
        make_float4(alpha, beta, gamma, delta);
    return;
  }
  id -= 3900;
  if (id < nz4) {  // zero logits
    reinterpret_cast<float4*>(ws + LG_OFF)[id] = make_float4(0.f, 0.f, 0.f, 0.f);
  }
}

// ---------------------------------------------------------------------------
// Transpose x[B][256] -> xT[256][B] via 64x64 LDS tiles (coalesced both ways).
// Requires B % 64 == 0 (guarded at launch).
// ---------------------------------------------------------------------------
__global__ __launch_bounds__(256) void transpose_kernel(
    const float* __restrict__ x, float* __restrict__ xT, int B) {
  __shared__ float t[64][65];
  const int tid = threadIdx.x;
  const int c0 = (blockIdx.x & 3) * 64;
  const int r0 = (blockIdx.x >> 2) * 64;
  const int rr = tid >> 4;   // 0..15
  const int cq = tid & 15;   // col quad
#pragma unroll
  for (int i = 0; i < 4; ++i) {
    int r = rr + i * 16;
    float4 v = *reinterpret_cast<const float4*>(
        x + (size_t)(r0 + r) * 256 + c0 + 4 * cq);
    t[r][4 * cq] = v.x; t[r][4 * cq + 1] = v.y;
    t[r][4 * cq + 2] = v.z; t[r][4 * cq + 3] = v.w;
  }
  __syncthreads();
#pragma unroll
  for (int i = 0; i < 4; ++i) {
    int c = rr + i * 16;
    int rq = cq;
    float4 v = make_float4(t[4 * rq][c], t[4 * rq + 1][c],
                           t[4 * rq + 2][c], t[4 * rq + 3][c]);
    *reinterpret_cast<float4*>(xT + (size_t)(c0 + c) * B + r0 + 4 * rq) = v;
  }
}

__device__ __forceinline__ float gate4(float4 cv, float a0, float a1) {
  return fmaf(cv.w, a0 * a1, fmaf(cv.z, a1, fmaf(cv.y, a0, cv.x)));
}
__device__ __forceinline__ float4 vload4(const float* p) {
  return *reinterpret_cast<const float4*>(p);
}
__device__ __forceinline__ float f4c(const float4& v, int c) {
  return c == 0 ? v.x : (c == 1 ? v.y : (c == 2 ? v.z : v.w));
}

// 64 consecutive LDS floats = weight cols (2P,2P+1); consume immediately
__device__ __forceinline__ void dotp32(const float* wp, const float* inp,
                                       float& a0, float& a1) {
#pragma unroll
  for (int t = 0; t < 8; ++t) {
    float4 wA = vload4(wp + 4 * t);
    float4 wB = vload4(wp + 32 + 4 * t);
    a0 = fmaf(inp[4 * t + 0], wA.x, a0);
    a0 = fmaf(inp[4 * t + 1], wA.y, a0);
    a0 = fmaf(inp[4 * t + 2], wA.z, a0);
    a0 = fmaf(inp[4 * t + 3], wA.w, a0);
    a1 = fmaf(inp[4 * t + 0], wB.x, a1);
    a1 = fmaf(inp[4 * t + 1], wB.y, a1);
    a1 = fmaf(inp[4 * t + 2], wB.z, a1);
    a1 = fmaf(inp[4 * t + 3], wB.w, a1);
  }
}
// two 28-float LDS strips (26 used) = weight cols (2q,2q+1)
__device__ __forceinline__ void dotp26(const float* wp, const float* h,
                                       float& a0, float& a1) {
#pragma unroll
  for (int t = 0; t < 7; ++t) {
    float4 wA = vload4(wp + 4 * t);
    float4 wB = vload4(wp + 28 + 4 * t);
#pragma unroll
    for (int c = 0; c < 4; ++c) {
      int j = 4 * t + c;
      if (j < 26) {
        a0 = fmaf(h[j], f4c(wA, c), a0);
        a1 = fmaf(h[j], f4c(wB, c), a1);
      }
    }
  }
}

// ---------------------------------------------------------------------------
// Chain kernel: thread = sample (256-sample tile), 1 chain per WG.
// Weights+coeffs for the chain staged into static LDS (19.6 KB -> 8 WGs/CU),
// streamed via uniform ds_read_b128. x via transposed xT (coalesced scalar
// loads, consecutive lanes = consecutive samples) or r10 fallback.
// Grid = (B/256) * 50 = 3200 WGs (~12.5/CU). Logits: global atomicAdd.
// ---------------------------------------------------------------------------
static constexpr int LW0_F = 52 * 32;  // 1664
static constexpr int LW1_F = 52 * 28;  // 1456
static constexpr int LW2_F = 52 * 28;  // 1456

template <bool XT>
__global__ __launch_bounds__(NT, 8) void chain_kernel(
    const float* __restrict__ x, const float* __restrict__ xTp,
    const float* __restrict__ ws, float* __restrict__ lgout, int B) {
  __shared__ float lw0[LW0_F];
  __shared__ float lw1[LW1_F];
  __shared__ float lw2[LW2_F];
  __shared__ float4 lcf[78];

  const int tid = threadIdx.x;
  const int bid = blockIdx.x;
  const int K = bid % 50;
  const int tile = bid / 50;
  const int s0 = tile * NT;

  // ---- stage this chain's weights + coeffs (coalesced float4 copies) ----
  {
    const float4* sa = reinterpret_cast<const float4*>(ws + W0T_OFF) +
                       (size_t)K * 416;
    float4* da = reinterpret_cast<float4*>(lw0);
    for (int i = tid; i < 416; i += NT) da[i] = sa[i];
    const float4* sb = reinterpret_cast<const float4*>(ws + W1T_OFF) +
                       (size_t)K * 364;
    float4* db = reinterpret_cast<float4*>(lw1);
    for (int i = tid; i < 364; i += NT) db[i] = sb[i];
    const float4* sc4 = reinterpret_cast<const float4*>(ws + W2T_OFF) +
                        (size_t)K * 364;
    float4* dc = reinterpret_cast<float4*>(lw2);
    for (int i = tid; i < 364; i += NT) dc[i] = sc4[i];
    const float4* cfg = reinterpret_cast<const float4*>(ws + CF_OFF);
    for (int i = tid; i < 78; i += NT) {
      int L = i / 26, q = i - L * 26;
      lcf[i] = cfg[L * 1300 + K * 26 + q];
    }
  }
  __syncthreads();

  const int s = s0 + tid;
  const bool valid = (s < B);
  const int sc = valid ? s : (B - 1);

  const int cs = 52 * K;
  const int nlo = cs / 325;
  const int nhi = (cs + 51) / 325;
  const int split = (nhi > nlo) ? (325 * nhi - cs) : 52;
  const int t1 = split >> 1;
  const int odd = split & 1;
  const float4* cf0 = lcf;
  const float4* cf1 = lcf + 26;
  const float4* cf2 = lcf + 52;

  float h[26];
  float inp[32];

  auto load_block = [&](int nb) {
    if (XT) {
#pragma unroll
      for (int j = 0; j < 32; ++j)
        inp[j] = xTp[(size_t)(nb * 32 + j) * B + sc];
    } else {
      const float* xs = x + (size_t)sc * 256 + nb * 32;
#pragma unroll
      for (int t = 0; t < 8; ++t) {
        float4 v = vload4(xs + 4 * t);
        inp[4 * t] = v.x; inp[4 * t + 1] = v.y;
        inp[4 * t + 2] = v.z; inp[4 * t + 3] = v.w;
      }
    }
  };

  load_block(nlo);

  // ---- layer 1, phase A (block nlo) ----
#pragma unroll
  for (int P = 0; P < 26; ++P) {
    if (P < t1) {
      float a0 = 0.f, a1 = 0.f;
      dotp32(lw0 + 2 * P * 32, inp, a0, a1);
      h[P] = gate4(cf0[P], a0, a1);
    }
  }
  // ---- straddle + phase B (block nhi) ----
  if (nhi > nlo) {
    float a0s = 0.f, a1s = 0.f, gs = 0.f;
    if (odd) {
      const float* wp = lw0 + 2 * t1 * 32;
#pragma unroll
      for (int t = 0; t < 8; ++t) {
        float4 w4 = vload4(wp + 4 * t);
        a0s = fmaf(inp[4 * t + 0], w4.x, a0s);
        a0s = fmaf(inp[4 * t + 1], w4.y, a0s);
        a0s = fmaf(inp[4 * t + 2], w4.z, a0s);
        a0s = fmaf(inp[4 * t + 3], w4.w, a0s);
      }
    }
    load_block(nhi);
    if (odd) {
      const float* wq = lw0 + (2 * t1 + 1) * 32;
#pragma unroll
      for (int t = 0; t < 8; ++t) {
        float4 w4 = vload4(wq + 4 * t);
        a1s = fmaf(inp[4 * t + 0], w4.x, a1s);
        a1s = fmaf(inp[4 * t + 1], w4.y, a1s);
        a1s = fmaf(inp[4 * t + 2], w4.z, a1s);
        a1s = fmaf(inp[4 * t + 3], w4.w, a1s);
      }
      gs = gate4(cf0[t1], a0s, a1s);
    }
#pragma unroll
    for (int P = 0; P < 26; ++P) {
      if (P >= t1 + odd) {
        float a0 = 0.f, a1 = 0.f;
        dotp32(lw0 + 2 * P * 32, inp, a0, a1);
        h[P] = gate4(cf0[P], a0, a1);
      }
    }
    if (odd) {  // static-index select for the register write
#pragma unroll
      for (int P = 0; P < 26; ++P)
        if (P == t1) h[P] = gs;
    }
  }

  // ---- layer 2 ----
  float h2[26];
#pragma unroll
  for (int q = 0; q < 26; ++q) {
    float a0 = 0.f, a1 = 0.f;
    dotp26(lw1 + 2 * q * 28, h, a0, a1);
    h2[q] = gate4(cf1[q], a0, a1);
  }

  // ---- layer 3 + chain sum ----
  float psum = 0.f;
#pragma unroll 2
  for (int q = 0; q < 26; ++q) {
    float a0 = 0.f, a1 = 0.f;
    dotp26(lw2 + 2 * q * 28, h2, a0, a1);
    psum += gate4(cf2[q], a0, a1);
  }
  if (valid) atomicAdd(&lgout[(size_t)s * 10 + K / 5], psum);
}

// ---------------------------------------------------------------------------
// Finalize: per-sample 10-way softmax.
// ---------------------------------------------------------------------------
__global__ __launch_bounds__(256) void softmax_kernel(
    const float* __restrict__ lgin, float* __restrict__ out, int B) {
  int s = blockIdx.x * 256 + threadIdx.x;
  if (s >= B) return;
  float lg[10];
#pragma unroll
  for (int c = 0; c < 10; ++c) lg[c] = lgin[(size_t)s * 10 + c];
  float mx = lg[0];
#pragma unroll
  for (int c = 1; c < 10; ++c) mx = fmaxf(mx, lg[c]);
  float ssum = 0.f;
#pragma unroll
  for (int c = 0; c < 10; ++c) { lg[c] = __expf(lg[c] - mx); ssum += lg[c]; }
  float inv = 1.f / ssum;
  float* o = out + (size_t)s * 10;
#pragma unroll
  for (int c = 0; c < 10; ++c) o[c] = lg[c] * inv;
}

extern "C" void kernel_launch(void* const* d_in, const int* in_sizes, int n_in,
                              void* d_out, int out_size, void* d_ws, size_t ws_size,
                              hipStream_t stream) {
  const float* x  = (const float*)d_in[0];
  const float* c0 = (const float*)d_in[1];
  const float* w0 = (const float*)d_in[2];
  const float* c1 = (const float*)d_in[3];
  const float* w1 = (const float*)d_in[4];
  const float* c2 = (const float*)d_in[5];
  const float* w2 = (const float*)d_in[6];
  float* out = (float*)d_out;
  float* ws  = (float*)d_ws;
  const int B = in_sizes[0] / 256;

  const int nz4 = (B * 10 + 3) / 4;
  const int npre = 11700 + nz4;
  precompute_kernel<<<(npre + 255) / 256, 256, 0, stream>>>(
      c0, w0, c1, w1, c2, w2, ws, nz4);

  const size_t need = ((size_t)XT_OFF + 256 * (size_t)B) * sizeof(float);
  const bool useXT = (ws_size >= need) && ((B & 63) == 0);

  const int nblk = (B + NT - 1) / NT;
  if (useXT) {
    transpose_kernel<<<(B / 64) * 4, 256, 0, stream>>>(x, ws + XT_OFF, B);
    chain_kernel<true><<<nblk * 50, NT, 0, stream>>>(x, ws + XT_OFF, ws,
                                                     ws + LG_OFF, B);
  } else {
    chain_kernel<false><<<nblk * 50, NT, 0, stream>>>(x, nullptr, ws,
                                                      ws + LG_OFF, B);
  }
  softmax_kernel<<<(B + 255) / 256, 256, 0, stream>>>(ws + LG_OFF, out, B);
}

// Round 12
// 361.727 us; speedup vs baseline: 1.3554x; 1.3554x over previous
//
#include <hip/hip_runtime.h>
#include <cstdint>

#define NT 256

// ws float offsets
static constexpr int W0T_OFF = 0;        // w0T[gc][32] : [2600][32] = 83200
static constexpr int W1T_OFF = 83200;    // w1T[k][o][28] : [50][52][28] = 72800
static constexpr int W2T_OFF = 156000;   // w2T[k][o][28] : 72800
static constexpr int CF_OFF  = 228800;   // gate coeffs float4 [3][1300] = 15600 floats
static constexpr int LG_OFF  = 244400;   // logits [B][10] f32
static constexpr int XT_OFF  = 408576;   // xT[256][B] (used only if ws_size allows)

// ---------------------------------------------------------------------------
// Precompute: softmax conn weights (axis=1) stored per-column contiguous,
// collapse 16-gate bank to gate(A,B) = a + b*A + c*B + d*A*B, zero logits.
// ---------------------------------------------------------------------------
__global__ void precompute_kernel(const float* __restrict__ c0,
                                  const float* __restrict__ w0,
                                  const float* __restrict__ c1,
                                  const float* __restrict__ w1,
                                  const float* __restrict__ c2,
                                  const float* __restrict__ w2,
                                  float* __restrict__ ws, int nz4) {
  int id = blockIdx.x * blockDim.x + threadIdx.x;
  if (id < 2600) {  // layer-1 col gc=(n,o): softmax over m=32 (stride 325 in src)
    int n = id / 325, o = id - n * 325;
    const float* src = c0 + n * (32 * 325) + o;
    float v[32]; float mx = -3.4e38f;
#pragma unroll
    for (int m = 0; m < 32; ++m) { v[m] = src[m * 325]; mx = fmaxf(mx, v[m]); }
    float ssum = 0.f;
#pragma unroll
    for (int m = 0; m < 32; ++m) { v[m] = __expf(v[m] - mx); ssum += v[m]; }
    float inv = 1.f / ssum;
    float* dst = ws + W0T_OFF + (size_t)id * 32;
#pragma unroll
    for (int m = 0; m < 32; ++m) dst[m] = v[m] * inv;
    return;
  }
  id -= 2600;
  if (id < 5200) {  // layer-2/3 col (k,o): softmax over m=26, pad stride 28
    const float* src0 = (id < 2600) ? c1 : c2;
    float* dst0 = ws + ((id < 2600) ? W1T_OFF : W2T_OFF);
    int col = (id < 2600) ? id : id - 2600;
    int k = col / 52, o = col - k * 52;
    const float* src = src0 + k * (26 * 52) + o;
    float v[26]; float mx = -3.4e38f;
#pragma unroll
    for (int m = 0; m < 26; ++m) { v[m] = src[m * 52]; mx = fmaxf(mx, v[m]); }
    float ssum = 0.f;
#pragma unroll
    for (int m = 0; m < 26; ++m) { v[m] = __expf(v[m] - mx); ssum += v[m]; }
    float inv = 1.f / ssum;
    float* dst = dst0 + (size_t)(k * 52 + o) * 28;
#pragma unroll
    for (int m = 0; m < 26; ++m) dst[m] = v[m] * inv;
    dst[26] = 0.f; dst[27] = 0.f;
    return;
  }
  id -= 5200;
  if (id < 3900) {  // gate coefficients
    int layer = id / 1300, g = id - layer * 1300;
    const float* w = (layer == 0) ? w0 : ((layer == 1) ? w1 : w2);
    float v[16]; float mx = -3.4e38f;
#pragma unroll
    for (int k = 0; k < 16; ++k) { v[k] = w[k * 1300 + g]; mx = fmaxf(mx, v[k]); }
    float ssum = 0.f;
#pragma unroll
    for (int k = 0; k < 16; ++k) { v[k] = __expf(v[k] - mx); ssum += v[k]; }
    float inv = 1.f / ssum;
#pragma unroll
    for (int k = 0; k < 16; ++k) v[k] *= inv;
    float alpha = v[8] + v[9] + v[10] + v[11] + v[12] + v[13] + v[14] + v[15];
    float beta  = v[2] + v[3] + v[6] + v[7] - v[8] - v[9] - v[12] - v[13];
    float gamma = v[4] + v[5] + v[6] + v[7] - v[8] - v[9] - v[10] - v[11];
    float delta = v[1] - v[2] - v[4] - 2.f * v[6] - v[7] + v[8] + 2.f * v[9]
                + v[11] + v[13] - v[14];
    reinterpret_cast<float4*>(ws + CF_OFF)[id] =
        make_float4(alpha, beta, gamma, delta);
    return;
  }
  id -= 3900;
  if (id < nz4) {  // zero logits
    reinterpret_cast<float4*>(ws + LG_OFF)[id] = make_float4(0.f, 0.f, 0.f, 0.f);
  }
}

// ---------------------------------------------------------------------------
// Transpose x[B][256] -> xT[256][B] via 64x64 LDS tiles (coalesced both ways).
// Requires B % 64 == 0 (guarded at launch).
// ---------------------------------------------------------------------------
__global__ __launch_bounds__(256) void transpose_kernel(
    const float* __restrict__ x, float* __restrict__ xT, int B) {
  __shared__ float t[64][65];
  const int tid = threadIdx.x;
  const int c0 = (blockIdx.x & 3) * 64;
  const int r0 = (blockIdx.x >> 2) * 64;
  const int rr = tid >> 4;   // 0..15
  const int cq = tid & 15;   // col quad
#pragma unroll
  for (int i = 0; i < 4; ++i) {
    int r = rr + i * 16;
    float4 v = *reinterpret_cast<const float4*>(
        x + (size_t)(r0 + r) * 256 + c0 + 4 * cq);
    t[r][4 * cq] = v.x; t[r][4 * cq + 1] = v.y;
    t[r][4 * cq + 2] = v.z; t[r][4 * cq + 3] = v.w;
  }
  __syncthreads();
#pragma unroll
  for (int i = 0; i < 4; ++i) {
    int c = rr + i * 16;
    int rq = cq;
    float4 v = make_float4(t[4 * rq][c], t[4 * rq + 1][c],
                           t[4 * rq + 2][c], t[4 * rq + 3][c]);
    *reinterpret_cast<float4*>(xT + (size_t)(c0 + c) * B + r0 + 4 * rq) = v;
  }
}

__device__ __forceinline__ float gate4(float4 cv, float a0, float a1) {
  return fmaf(cv.w, a0 * a1, fmaf(cv.z, a1, fmaf(cv.y, a0, cv.x)));
}
__device__ __forceinline__ float4 vload4(const float* p) {
  return *reinterpret_cast<const float4*>(p);
}
__device__ __forceinline__ float f4c(const float4& v, int c) {
  return c == 0 ? v.x : (c == 1 ? v.y : (c == 2 ? v.z : v.w));
}

// 64 consecutive LDS floats = weight cols (2P,2P+1); consume immediately
__device__ __forceinline__ void dotp32(const float* wp, const float* inp,
                                       float& a0, float& a1) {
#pragma unroll
  for (int t = 0; t < 8; ++t) {
    float4 wA = vload4(wp + 4 * t);
    float4 wB = vload4(wp + 32 + 4 * t);
    a0 = fmaf(inp[4 * t + 0], wA.x, a0);
    a0 = fmaf(inp[4 * t + 1], wA.y, a0);
    a0 = fmaf(inp[4 * t + 2], wA.z, a0);
    a0 = fmaf(inp[4 * t + 3], wA.w, a0);
    a1 = fmaf(inp[4 * t + 0], wB.x, a1);
    a1 = fmaf(inp[4 * t + 1], wB.y, a1);
    a1 = fmaf(inp[4 * t + 2], wB.z, a1);
    a1 = fmaf(inp[4 * t + 3], wB.w, a1);
  }
}
// two 28-float LDS strips (26 used) = weight cols (2q,2q+1)
__device__ __forceinline__ void dotp26(const float* wp, const float* h,
                                       float& a0, float& a1) {
#pragma unroll
  for (int t = 0; t < 7; ++t) {
    float4 wA = vload4(wp + 4 * t);
    float4 wB = vload4(wp + 28 + 4 * t);
#pragma unroll
    for (int c = 0; c < 4; ++c) {
      int j = 4 * t + c;
      if (j < 26) {
        a0 = fmaf(h[j], f4c(wA, c), a0);
        a1 = fmaf(h[j], f4c(wB, c), a1);
      }
    }
  }
}

// ---------------------------------------------------------------------------
// Chain kernel: thread = sample (256-sample tile), 1 chain per WG.
// Weights+coeffs staged into static LDS (19.6 KB), streamed via uniform
// ds_read_b128. x via transposed xT (coalesced: consecutive lanes =
// consecutive samples). Grid = (B/256) * 50 = 3200 WGs.
// __launch_bounds__(256, 6): VGPR cap 85 — the validated no-spill regime
// (r5/r10). r11's (256,8) capped at 64 and spilled (430 MB scratch writes).
// ---------------------------------------------------------------------------
static constexpr int LW0_F = 52 * 32;  // 1664
static constexpr int LW1_F = 52 * 28;  // 1456
static constexpr int LW2_F = 52 * 28;  // 1456

template <bool XT>
__global__ __launch_bounds__(NT, 6) void chain_kernel(
    const float* __restrict__ x, const float* __restrict__ xTp,
    const float* __restrict__ ws, float* __restrict__ lgout, int B) {
  __shared__ float lw0[LW0_F];
  __shared__ float lw1[LW1_F];
  __shared__ float lw2[LW2_F];
  __shared__ float4 lcf[78];

  const int tid = threadIdx.x;
  const int bid = blockIdx.x;
  const int K = bid % 50;
  const int tile = bid / 50;
  const int s0 = tile * NT;

  // ---- stage this chain's weights + coeffs (coalesced float4 copies) ----
  {
    const float4* sa = reinterpret_cast<const float4*>(ws + W0T_OFF) +
                       (size_t)K * 416;
    float4* da = reinterpret_cast<float4*>(lw0);
    for (int i = tid; i < 416; i += NT) da[i] = sa[i];
    const float4* sb = reinterpret_cast<const float4*>(ws + W1T_OFF) +
                       (size_t)K * 364;
    float4* db = reinterpret_cast<float4*>(lw1);
    for (int i = tid; i < 364; i += NT) db[i] = sb[i];
    const float4* sc4 = reinterpret_cast<const float4*>(ws + W2T_OFF) +
                        (size_t)K * 364;
    float4* dc = reinterpret_cast<float4*>(lw2);
    for (int i = tid; i < 364; i += NT) dc[i] = sc4[i];
    const float4* cfg = reinterpret_cast<const float4*>(ws + CF_OFF);
    for (int i = tid; i < 78; i += NT) {
      int L = i / 26, q = i - L * 26;
      lcf[i] = cfg[L * 1300 + K * 26 + q];
    }
  }
  __syncthreads();

  const int s = s0 + tid;
  const bool valid = (s < B);
  const int sc = valid ? s : (B - 1);

  const int cs = 52 * K;
  const int nlo = cs / 325;
  const int nhi = (cs + 51) / 325;
  const int split = (nhi > nlo) ? (325 * nhi - cs) : 52;
  const int t1 = split >> 1;
  const int odd = split & 1;
  const float4* cf0 = lcf;
  const float4* cf1 = lcf + 26;
  const float4* cf2 = lcf + 52;

  float h[26];
  float inp[32];

  auto load_block = [&](int nb) {
    if (XT) {
#pragma unroll
      for (int j = 0; j < 32; ++j)
        inp[j] = xTp[(size_t)(nb * 32 + j) * B + sc];
    } else {
      const float* xs = x + (size_t)sc * 256 + nb * 32;
#pragma unroll
      for (int t = 0; t < 8; ++t) {
        float4 v = vload4(xs + 4 * t);
        inp[4 * t] = v.x; inp[4 * t + 1] = v.y;
        inp[4 * t + 2] = v.z; inp[4 * t + 3] = v.w;
      }
    }
  };

  load_block(nlo);

  // ---- layer 1, phase A (block nlo) ----
#pragma unroll
  for (int P = 0; P < 26; ++P) {
    if (P < t1) {
      float a0 = 0.f, a1 = 0.f;
      dotp32(lw0 + 2 * P * 32, inp, a0, a1);
      h[P] = gate4(cf0[P], a0, a1);
    }
  }
  // ---- straddle + phase B (block nhi) ----
  if (nhi > nlo) {
    float a0s = 0.f, a1s = 0.f, gs = 0.f;
    if (odd) {
      const float* wp = lw0 + 2 * t1 * 32;
#pragma unroll
      for (int t = 0; t < 8; ++t) {
        float4 w4 = vload4(wp + 4 * t);
        a0s = fmaf(inp[4 * t + 0], w4.x, a0s);
        a0s = fmaf(inp[4 * t + 1], w4.y, a0s);
        a0s = fmaf(inp[4 * t + 2], w4.z, a0s);
        a0s = fmaf(inp[4 * t + 3], w4.w, a0s);
      }
    }
    load_block(nhi);
    if (odd) {
      const float* wq = lw0 + (2 * t1 + 1) * 32;
#pragma unroll
      for (int t = 0; t < 8; ++t) {
        float4 w4 = vload4(wq + 4 * t);
        a1s = fmaf(inp[4 * t + 0], w4.x, a1s);
        a1s = fmaf(inp[4 * t + 1], w4.y, a1s);
        a1s = fmaf(inp[4 * t + 2], w4.z, a1s);
        a1s = fmaf(inp[4 * t + 3], w4.w, a1s);
      }
      gs = gate4(cf0[t1], a0s, a1s);
    }
#pragma unroll
    for (int P = 0; P < 26; ++P) {
      if (P >= t1 + odd) {
        float a0 = 0.f, a1 = 0.f;
        dotp32(lw0 + 2 * P * 32, inp, a0, a1);
        h[P] = gate4(cf0[P], a0, a1);
      }
    }
    if (odd) {  // static-index select for the register write
#pragma unroll
      for (int P = 0; P < 26; ++P)
        if (P == t1) h[P] = gs;
    }
  }

  // ---- layer 2 ----
  float h2[26];
#pragma unroll
  for (int q = 0; q < 26; ++q) {
    float a0 = 0.f, a1 = 0.f;
    dotp26(lw1 + 2 * q * 28, h, a0, a1);
    h2[q] = gate4(cf1[q], a0, a1);
  }

  // ---- layer 3 + chain sum ----
  float psum = 0.f;
#pragma unroll 2
  for (int q = 0; q < 26; ++q) {
    float a0 = 0.f, a1 = 0.f;
    dotp26(lw2 + 2 * q * 28, h2, a0, a1);
    psum += gate4(cf2[q], a0, a1);
  }
  if (valid) atomicAdd(&lgout[(size_t)s * 10 + K / 5], psum);
}

// ---------------------------------------------------------------------------
// Finalize: per-sample 10-way softmax.
// ---------------------------------------------------------------------------
__global__ __launch_bounds__(256) void softmax_kernel(
    const float* __restrict__ lgin, float* __restrict__ out, int B) {
  int s = blockIdx.x * 256 + threadIdx.x;
  if (s >= B) return;
  float lg[10];
#pragma unroll
  for (int c = 0; c < 10; ++c) lg[c] = lgin[(size_t)s * 10 + c];
  float mx = lg[0];
#pragma unroll
  for (int c = 1; c < 10; ++c) mx = fmaxf(mx, lg[c]);
  float ssum = 0.f;
#pragma unroll
  for (int c = 0; c < 10; ++c) { lg[c] = __expf(lg[c] - mx); ssum += lg[c]; }
  float inv = 1.f / ssum;
  float* o = out + (size_t)s * 10;
#pragma unroll
  for (int c = 0; c < 10; ++c) o[c] = lg[c] * inv;
}

extern "C" void kernel_launch(void* const* d_in, const int* in_sizes, int n_in,
                              void* d_out, int out_size, void* d_ws, size_t ws_size,
                              hipStream_t stream) {
  const float* x  = (const float*)d_in[0];
  const float* c0 = (const float*)d_in[1];
  const float* w0 = (const float*)d_in[2];
  const float* c1 = (const float*)d_in[3];
  const float* w1 = (const float*)d_in[4];
  const float* c2 = (const float*)d_in[5];
  const float* w2 = (const float*)d_in[6];
  float* out = (float*)d_out;
  float* ws  = (float*)d_ws;
  const int B = in_sizes[0] / 256;

  const int nz4 = (B * 10 + 3) / 4;
  const int npre = 11700 + nz4;
  precompute_kernel<<<(npre + 255) / 256, 256, 0, stream>>>(
      c0, w0, c1, w1, c2, w2, ws, nz4);

  const size_t need = ((size_t)XT_OFF + 256 * (size_t)B) * sizeof(float);
  const bool useXT = (ws_size >= need) && ((B & 63) == 0);

  const int nblk = (B + NT - 1) / NT;
  if (useXT) {
    transpose_kernel<<<(B / 64) * 4, 256, 0, stream>>>(x, ws + XT_OFF, B);
    chain_kernel<true><<<nblk * 50, NT, 0, stream>>>(x, ws + XT_OFF, ws,
                                                     ws + LG_OFF, B);
  } else {
    chain_kernel<false><<<nblk * 50, NT, 0, stream>>>(x, nullptr, ws,
                                                      ws + LG_OFF, B);
  }
  softmax_kernel<<<(B + 255) / 256, 256, 0, stream>>>(ws + LG_OFF, out, B);
}

// Round 13
// 186.100 us; speedup vs baseline: 2.6345x; 1.9437x over previous
//
#include <hip/hip_runtime.h>
#include <cstdint>

#define NT 256

// ws float offsets
static constexpr int W0T_OFF = 0;        // w0T[gc][32] : [2600][32] = 83200
static constexpr int W1T_OFF = 83200;    // w1T[k][o][28] : [50][52][28] = 72800
static constexpr int W2T_OFF = 156000;   // w2T[k][o][28] : 72800
static constexpr int CF_OFF  = 228800;   // gate coeffs float4 [3][1300] = 15600 floats
static constexpr int LG_OFF  = 244400;   // logits: [50][B] partials (LGP) or [B][10] (atomic)

// ---------------------------------------------------------------------------
// Precompute: softmax conn weights (axis=1) stored per-column contiguous,
// collapse 16-gate bank to gate(A,B) = a + b*A + c*B + d*A*B, zero logits.
// ---------------------------------------------------------------------------
__global__ void precompute_kernel(const float* __restrict__ c0,
                                  const float* __restrict__ w0,
                                  const float* __restrict__ c1,
                                  const float* __restrict__ w1,
                                  const float* __restrict__ c2,
                                  const float* __restrict__ w2,
                                  float* __restrict__ ws, int nz4) {
  int id = blockIdx.x * blockDim.x + threadIdx.x;
  if (id < 2600) {  // layer-1 col gc=(n,o): softmax over m=32 (stride 325 in src)
    int n = id / 325, o = id - n * 325;
    const float* src = c0 + n * (32 * 325) + o;
    float v[32]; float mx = -3.4e38f;
#pragma unroll
    for (int m = 0; m < 32; ++m) { v[m] = src[m * 325]; mx = fmaxf(mx, v[m]); }
    float ssum = 0.f;
#pragma unroll
    for (int m = 0; m < 32; ++m) { v[m] = __expf(v[m] - mx); ssum += v[m]; }
    float inv = 1.f / ssum;
    float* dst = ws + W0T_OFF + (size_t)id * 32;
#pragma unroll
    for (int m = 0; m < 32; ++m) dst[m] = v[m] * inv;
    return;
  }
  id -= 2600;
  if (id < 5200) {  // layer-2/3 col (k,o): softmax over m=26, pad stride 28
    const float* src0 = (id < 2600) ? c1 : c2;
    float* dst0 = ws + ((id < 2600) ? W1T_OFF : W2T_OFF);
    int col = (id < 2600) ? id : id - 2600;
    int k = col / 52, o = col - k * 52;
    const float* src = src0 + k * (26 * 52) + o;
    float v[26]; float mx = -3.4e38f;
#pragma unroll
    for (int m = 0; m < 26; ++m) { v[m] = src[m * 52]; mx = fmaxf(mx, v[m]); }
    float ssum = 0.f;
#pragma unroll
    for (int m = 0; m < 26; ++m) { v[m] = __expf(v[m] - mx); ssum += v[m]; }
    float inv = 1.f / ssum;
    float* dst = dst0 + (size_t)(k * 52 + o) * 28;
#pragma unroll
    for (int m = 0; m < 26; ++m) dst[m] = v[m] * inv;
    dst[26] = 0.f; dst[27] = 0.f;
    return;
  }
  id -= 5200;
  if (id < 3900) {  // gate coefficients
    int layer = id / 1300, g = id - layer * 1300;
    const float* w = (layer == 0) ? w0 : ((layer == 1) ? w1 : w2);
    float v[16]; float mx = -3.4e38f;
#pragma unroll
    for (int k = 0; k < 16; ++k) { v[k] = w[k * 1300 + g]; mx = fmaxf(mx, v[k]); }
    float ssum = 0.f;
#pragma unroll
    for (int k = 0; k < 16; ++k) { v[k] = __expf(v[k] - mx); ssum += v[k]; }
    float inv = 1.f / ssum;
#pragma unroll
    for (int k = 0; k < 16; ++k) v[k] *= inv;
    float alpha = v[8] + v[9] + v[10] + v[11] + v[12] + v[13] + v[14] + v[15];
    float beta  = v[2] + v[3] + v[6] + v[7] - v[8] - v[9] - v[12] - v[13];
    float gamma = v[4] + v[5] + v[6] + v[7] - v[8] - v[9] - v[10] - v[11];
    float delta = v[1] - v[2] - v[4] - 2.f * v[6] - v[7] + v[8] + 2.f * v[9]
                + v[11] + v[13] - v[14];
    reinterpret_cast<float4*>(ws + CF_OFF)[id] =
        make_float4(alpha, beta, gamma, delta);
    return;
  }
  id -= 3900;
  if (id < nz4) {  // zero logits (needed for the atomic fallback path)
    reinterpret_cast<float4*>(ws + LG_OFF)[id] = make_float4(0.f, 0.f, 0.f, 0.f);
  }
}

__device__ __forceinline__ float gate4(float4 cv, float a0, float a1) {
  return fmaf(cv.w, a0 * a1, fmaf(cv.z, a1, fmaf(cv.y, a0, cv.x)));
}
__device__ __forceinline__ float4 vload4(const float* p) {
  return *reinterpret_cast<const float4*>(p);
}
__device__ __forceinline__ float f4c(const float4& v, int c) {
  return c == 0 ? v.x : (c == 1 ? v.y : (c == 2 ? v.z : v.w));
}

// 64 consecutive LDS floats = weight cols (2P,2P+1); consume immediately
__device__ __forceinline__ void dotp32(const float* wp, const float* inp,
                                       float& a0, float& a1) {
#pragma unroll
  for (int t = 0; t < 8; ++t) {
    float4 wA = vload4(wp + 4 * t);
    float4 wB = vload4(wp + 32 + 4 * t);
    a0 = fmaf(inp[4 * t + 0], wA.x, a0);
    a0 = fmaf(inp[4 * t + 1], wA.y, a0);
    a0 = fmaf(inp[4 * t + 2], wA.z, a0);
    a0 = fmaf(inp[4 * t + 3], wA.w, a0);
    a1 = fmaf(inp[4 * t + 0], wB.x, a1);
    a1 = fmaf(inp[4 * t + 1], wB.y, a1);
    a1 = fmaf(inp[4 * t + 2], wB.z, a1);
    a1 = fmaf(inp[4 * t + 3], wB.w, a1);
  }
}
// two 28-float LDS strips (26 used) = weight cols (2q,2q+1)
__device__ __forceinline__ void dotp26(const float* wp, const float* h,
                                       float& a0, float& a1) {
#pragma unroll
  for (int t = 0; t < 7; ++t) {
    float4 wA = vload4(wp + 4 * t);
    float4 wB = vload4(wp + 28 + 4 * t);
#pragma unroll
    for (int c = 0; c < 4; ++c) {
      int j = 4 * t + c;
      if (j < 26) {
        a0 = fmaf(h[j], f4c(wA, c), a0);
        a1 = fmaf(h[j], f4c(wB, c), a1);
      }
    }
  }
}

// ---------------------------------------------------------------------------
// Chain kernel: thread = sample (256-sample tile), 1 chain per WG.
// Weights+coeffs staged into static LDS (19.6 KB), streamed via uniform
// ds_read_b128 (counted-lgkm, pipelinable).
// XCD CO-LOCATION SWIZZLE: K = bid / nblk, tile = bid % nblk. With
// nblk % 8 == 0, all 50 WGs of tile t land on XCD t%8 (bid % 8 == t % 8)
// -> x tile + logit lines stay in ONE L2; weights (1.3 MB) L2-resident
// everywhere. r12's mapping spread a tile's WGs over all 8 XCDs (660 MB
// of cross-XCD refetch = the measured memory-bound stall).
// LGP=true: partial logits to lgp[K][B], coalesced plain stores (no
// atomics, deterministic). LGP=false: r12's atomicAdd [B][10] fallback.
// __launch_bounds__(256,6): VGPR cap 85 — validated no-spill regime.
// ---------------------------------------------------------------------------
static constexpr int LW0_F = 52 * 32;  // 1664
static constexpr int LW1_F = 52 * 28;  // 1456
static constexpr int LW2_F = 52 * 28;  // 1456

template <bool LGP>
__global__ __launch_bounds__(NT, 6) void chain_kernel(
    const float* __restrict__ x, const float* __restrict__ ws,
    float* __restrict__ lgout, int B, int nblk) {
  __shared__ float lw0[LW0_F];
  __shared__ float lw1[LW1_F];
  __shared__ float lw2[LW2_F];
  __shared__ float4 lcf[78];

  const int tid = threadIdx.x;
  const int bid = blockIdx.x;
  const int K = bid / nblk;        // chain  (swizzled: tile is the fast axis)
  const int tile = bid - K * nblk;
  const int s0 = tile * NT;

  // ---- stage this chain's weights + coeffs (coalesced float4 copies) ----
  {
    const float4* sa = reinterpret_cast<const float4*>(ws + W0T_OFF) +
                       (size_t)K * 416;
    float4* da = reinterpret_cast<float4*>(lw0);
    for (int i = tid; i < 416; i += NT) da[i] = sa[i];
    const float4* sb = reinterpret_cast<const float4*>(ws + W1T_OFF) +
                       (size_t)K * 364;
    float4* db = reinterpret_cast<float4*>(lw1);
    for (int i = tid; i < 364; i += NT) db[i] = sb[i];
    const float4* sc4 = reinterpret_cast<const float4*>(ws + W2T_OFF) +
                        (size_t)K * 364;
    float4* dc = reinterpret_cast<float4*>(lw2);
    for (int i = tid; i < 364; i += NT) dc[i] = sc4[i];
    const float4* cfg = reinterpret_cast<const float4*>(ws + CF_OFF);
    for (int i = tid; i < 78; i += NT) {
      int L = i / 26, q = i - L * 26;
      lcf[i] = cfg[L * 1300 + K * 26 + q];
    }
  }
  __syncthreads();

  const int s = s0 + tid;
  const bool valid = (s < B);
  const int sc = valid ? s : (B - 1);

  const int cs = 52 * K;
  const int nlo = cs / 325;
  const int nhi = (cs + 51) / 325;
  const int split = (nhi > nlo) ? (325 * nhi - cs) : 52;
  const int t1 = split >> 1;
  const int odd = split & 1;
  const float4* cf0 = lcf;
  const float4* cf1 = lcf + 26;
  const float4* cf2 = lcf + 52;

  float h[26];
  float inp[32];

  auto load_block = [&](int nb) {
    const float* xs = x + (size_t)sc * 256 + nb * 32;
#pragma unroll
    for (int t = 0; t < 8; ++t) {
      float4 v = vload4(xs + 4 * t);
      inp[4 * t] = v.x; inp[4 * t + 1] = v.y;
      inp[4 * t + 2] = v.z; inp[4 * t + 3] = v.w;
    }
  };

  load_block(nlo);

  // ---- layer 1, phase A (block nlo) ----
#pragma unroll
  for (int P = 0; P < 26; ++P) {
    if (P < t1) {
      float a0 = 0.f, a1 = 0.f;
      dotp32(lw0 + 2 * P * 32, inp, a0, a1);
      h[P] = gate4(cf0[P], a0, a1);
    }
  }
  // ---- straddle + phase B (block nhi) ----
  if (nhi > nlo) {
    float a0s = 0.f, a1s = 0.f, gs = 0.f;
    if (odd) {
      const float* wp = lw0 + 2 * t1 * 32;
#pragma unroll
      for (int t = 0; t < 8; ++t) {
        float4 w4 = vload4(wp + 4 * t);
        a0s = fmaf(inp[4 * t + 0], w4.x, a0s);
        a0s = fmaf(inp[4 * t + 1], w4.y, a0s);
        a0s = fmaf(inp[4 * t + 2], w4.z, a0s);
        a0s = fmaf(inp[4 * t + 3], w4.w, a0s);
      }
    }
    load_block(nhi);
    if (odd) {
      const float* wq = lw0 + (2 * t1 + 1) * 32;
#pragma unroll
      for (int t = 0; t < 8; ++t) {
        float4 w4 = vload4(wq + 4 * t);
        a1s = fmaf(inp[4 * t + 0], w4.x, a1s);
        a1s = fmaf(inp[4 * t + 1], w4.y, a1s);
        a1s = fmaf(inp[4 * t + 2], w4.z, a1s);
        a1s = fmaf(inp[4 * t + 3], w4.w, a1s);
      }
      gs = gate4(cf0[t1], a0s, a1s);
    }
#pragma unroll
    for (int P = 0; P < 26; ++P) {
      if (P >= t1 + odd) {
        float a0 = 0.f, a1 = 0.f;
        dotp32(lw0 + 2 * P * 32, inp, a0, a1);
        h[P] = gate4(cf0[P], a0, a1);
      }
    }
    if (odd) {  // static-index select for the register write
#pragma unroll
      for (int P = 0; P < 26; ++P)
        if (P == t1) h[P] = gs;
    }
  }

  // ---- layer 2 ----
  float h2[26];
#pragma unroll
  for (int q = 0; q < 26; ++q) {
    float a0 = 0.f, a1 = 0.f;
    dotp26(lw1 + 2 * q * 28, h, a0, a1);
    h2[q] = gate4(cf1[q], a0, a1);
  }

  // ---- layer 3 + chain sum ----
  float psum = 0.f;
#pragma unroll 2
  for (int q = 0; q < 26; ++q) {
    float a0 = 0.f, a1 = 0.f;
    dotp26(lw2 + 2 * q * 28, h2, a0, a1);
    psum += gate4(cf2[q], a0, a1);
  }
  if (valid) {
    if (LGP) lgout[(size_t)K * B + s] = psum;            // coalesced store
    else     atomicAdd(&lgout[(size_t)s * 10 + K / 5], psum);
  }
}

// ---------------------------------------------------------------------------
// Finalize: per-sample 10-way softmax (LGP: sum 5 chain-partials per class).
// ---------------------------------------------------------------------------
template <bool LGP>
__global__ __launch_bounds__(256) void softmax_kernel(
    const float* __restrict__ lgin, float* __restrict__ out, int B) {
  int s = blockIdx.x * 256 + threadIdx.x;
  if (s >= B) return;
  float lg[10];
  if (LGP) {
#pragma unroll
    for (int c = 0; c < 10; ++c) {
      float t = 0.f;
#pragma unroll
      for (int j = 0; j < 5; ++j) t += lgin[(size_t)(5 * c + j) * B + s];
      lg[c] = t;
    }
  } else {
#pragma unroll
    for (int c = 0; c < 10; ++c) lg[c] = lgin[(size_t)s * 10 + c];
  }
  float mx = lg[0];
#pragma unroll
  for (int c = 1; c < 10; ++c) mx = fmaxf(mx, lg[c]);
  float ssum = 0.f;
#pragma unroll
  for (int c = 0; c < 10; ++c) { lg[c] = __expf(lg[c] - mx); ssum += lg[c]; }
  float inv = 1.f / ssum;
  float* o = out + (size_t)s * 10;
#pragma unroll
  for (int c = 0; c < 10; ++c) o[c] = lg[c] * inv;
}

extern "C" void kernel_launch(void* const* d_in, const int* in_sizes, int n_in,
                              void* d_out, int out_size, void* d_ws, size_t ws_size,
                              hipStream_t stream) {
  const float* x  = (const float*)d_in[0];
  const float* c0 = (const float*)d_in[1];
  const float* w0 = (const float*)d_in[2];
  const float* c1 = (const float*)d_in[3];
  const float* w1 = (const float*)d_in[4];
  const float* c2 = (const float*)d_in[5];
  const float* w2 = (const float*)d_in[6];
  float* out = (float*)d_out;
  float* ws  = (float*)d_ws;
  const int B = in_sizes[0] / 256;

  const int nz4 = (B * 10 + 3) / 4;
  const int npre = 11700 + nz4;
  precompute_kernel<<<(npre + 255) / 256, 256, 0, stream>>>(
      c0, w0, c1, w1, c2, w2, ws, nz4);

  const bool useLGP =
      ws_size >= ((size_t)LG_OFF + (size_t)50 * B) * sizeof(float);

  const int nblk = (B + NT - 1) / NT;
  if (useLGP) {
    chain_kernel<true><<<nblk * 50, NT, 0, stream>>>(x, ws, ws + LG_OFF, B, nblk);
    softmax_kernel<true><<<(B + 255) / 256, 256, 0, stream>>>(ws + LG_OFF, out, B);
  } else {
    chain_kernel<false><<<nblk * 50, NT, 0, stream>>>(x, ws, ws + LG_OFF, B, nblk);
    softmax_kernel<false><<<(B + 255) / 256, 256, 0, stream>>>(ws + LG_OFF, out, B);
  }
}